// Round 4
// baseline (468.184 us; speedup 1.0000x reference)
//
#include <hip/hip_runtime.h>
#include <hip/hip_bf16.h>
#include <math.h>

#define B_ 4
#define S_ 2048
#define HID_ 768
#define NH_ 12
#define HD_ 64

typedef short bf16x8 __attribute__((ext_vector_type(8)));
typedef short bf16x4 __attribute__((ext_vector_type(4)));
typedef float f32x4 __attribute__((ext_vector_type(4)));
typedef unsigned short u16;
typedef unsigned int uu32;

#define QSCALE 0.18033688011112042f   /* 0.125 * log2(e) */
#define LOG2E  1.4426950408889634f
#define DEFER_THR 8.0f

__device__ __forceinline__ u16 f2bf(float f) {
  union { float f; unsigned u; } x; x.f = f;
  unsigned u = x.u;
  u += 0x7FFFu + ((u >> 16) & 1u);   // round-to-nearest-even
  return (u16)(u >> 16);
}

__device__ __forceinline__ float exp2_fast(float x) {
  float r;
  asm("v_exp_f32 %0, %1" : "=v"(r) : "v"(x));
  return r;
}

__device__ __forceinline__ uu32 cvt_pk_bf16(float lo, float hi) {
  uu32 r;
  asm("v_cvt_pk_bf16_f32 %0, %1, %2" : "=v"(r) : "v"(lo), "v"(hi));
  return r;
}

// ---------------- cast hidden fp32 -> bf16 ----------------
__global__ void cast_x(const float* __restrict__ x, u16* __restrict__ xb, int n) {
  int i = (blockIdx.x * 256 + threadIdx.x) * 4;
  if (i >= n) return;
  float4 v = *(const float4*)(x + i);
  ushort4 o;
  o.x = f2bf(v.x); o.y = f2bf(v.y); o.z = f2bf(v.z); o.w = f2bf(v.w);
  *(ushort4*)(xb + i) = o;
}

// ---------------- mask * log2e ----------------
__global__ void mask_scale(const float* __restrict__ m, float* __restrict__ o, int n) {
  int i = blockIdx.x * 256 + threadIdx.x;
  if (i < n) o[i] = m[i] * LOG2E;
}

// ------------- transpose + cast W[k][n] -> Wt[n][k] bf16 -------------
__global__ void wtrans(const float* __restrict__ Wq, const float* __restrict__ Wk,
                       const float* __restrict__ Wv, u16* __restrict__ wt) {
  const float* W = blockIdx.z == 0 ? Wq : (blockIdx.z == 1 ? Wk : Wv);
  u16* out = wt + (size_t)blockIdx.z * HID_ * HID_;
  __shared__ float t[32][33];
  int tx = threadIdx.x & 31, ty = threadIdx.x >> 5;   // 32 x 8
  int k0 = blockIdx.x * 32, n0 = blockIdx.y * 32;
#pragma unroll
  for (int i = 0; i < 4; i++)
    t[ty + 8 * i][tx] = W[(k0 + ty + 8 * i) * HID_ + n0 + tx];
  __syncthreads();
#pragma unroll
  for (int i = 0; i < 4; i++)
    out[(n0 + ty + 8 * i) * HID_ + k0 + tx] = f2bf(t[tx][ty + 8 * i]);
}

// ---------------- QKV projection GEMM ----------------
// z=0: Q (pre-scaled by 0.125*log2e), z=1: K, both [b,h,s,d].
// z=2: V written DIRECTLY transposed as Vt [b,h,d,s] (vtrans kernel fused away).
__global__ __launch_bounds__(256) void qkv_gemm(
    const u16* __restrict__ xb, const u16* __restrict__ wt_all,
    const float* __restrict__ bq, const float* __restrict__ bk,
    const float* __restrict__ bv,
    u16* __restrict__ q, u16* __restrict__ k_, u16* __restrict__ vt) {
  int z = blockIdx.z;
  const u16* wt = wt_all + (size_t)z * HID_ * HID_;
  const float* bias = z == 0 ? bq : (z == 1 ? bk : bv);

  int l = threadIdx.x & 63, w = threadIdx.x >> 6;
  int lr = l & 15, lg = l >> 4;
  int m0 = blockIdx.x * 128 + w * 32;
  int n0 = blockIdx.y * 64;

  f32x4 acc[2][4] = {};
  const u16* arow0 = xb + (size_t)(m0 + lr) * HID_ + 8 * lg;
  const u16* arow1 = arow0 + 16 * HID_;
  const u16* brow[4];
#pragma unroll
  for (int nt = 0; nt < 4; nt++)
    brow[nt] = wt + (size_t)(n0 + 16 * nt + lr) * HID_ + 8 * lg;

#pragma unroll 4
  for (int kk = 0; kk < HID_; kk += 32) {
    bf16x8 a0 = *(const bf16x8*)(arow0 + kk);
    bf16x8 a1 = *(const bf16x8*)(arow1 + kk);
#pragma unroll
    for (int nt = 0; nt < 4; nt++) {
      bf16x8 b = *(const bf16x8*)(brow[nt] + kk);
      acc[0][nt] = __builtin_amdgcn_mfma_f32_16x16x32_bf16(a0, b, acc[0][nt], 0, 0, 0);
      acc[1][nt] = __builtin_amdgcn_mfma_f32_16x16x32_bf16(a1, b, acc[1][nt], 0, 0, 0);
    }
  }

  int h = blockIdx.y;
  if (z == 2) {
    // Vt[bh][d][s]: lane holds 4 consecutive s (r=0..3) at fixed d -> 8B stores
#pragma unroll
    for (int mt = 0; mt < 2; mt++)
#pragma unroll
      for (int nt = 0; nt < 4; nt++) {
        float bval = bias[n0 + 16 * nt + lr];
        int m = m0 + 16 * mt + 4 * lg;
        int bidx = m >> 11, s = m & 2047;
        int d = 16 * nt + lr;
        ushort4 pk;
        pk.x = f2bf(acc[mt][nt][0] + bval);
        pk.y = f2bf(acc[mt][nt][1] + bval);
        pk.z = f2bf(acc[mt][nt][2] + bval);
        pk.w = f2bf(acc[mt][nt][3] + bval);
        *(ushort4*)(vt + ((size_t)(bidx * NH_ + h) * HD_ + d) * S_ + s) = pk;
      }
  } else {
    u16* out = z == 0 ? q : k_;
    float osc = z == 0 ? QSCALE : 1.0f;
#pragma unroll
    for (int mt = 0; mt < 2; mt++)
#pragma unroll
      for (int nt = 0; nt < 4; nt++) {
        float bval = bias[n0 + 16 * nt + lr];
#pragma unroll
        for (int r = 0; r < 4; r++) {
          int m = m0 + 16 * mt + 4 * lg + r;
          int bidx = m >> 11, s = m & 2047;
          out[(((size_t)(bidx * NH_ + h)) * S_ + s) * HD_ + 16 * nt + lr] =
              f2bf((acc[mt][nt][r] + bval) * osc);
        }
      }
  }
}

// ---------------- flash attention: swapped QK + shuffle-free PV ----------------
// PV contraction permutation pi(h2, 8*lg+j) = 16*(2h2+(j>>2)) + 4*lg + (j&3):
// P^T B-fragment = lane's OWN QK output regs (cvt_pk only, no cross-lane),
// V^T A-fragment = two 8B loads per fragment at permuted columns.
__global__ __launch_bounds__(256) void attn4(
    const u16* __restrict__ q, const u16* __restrict__ k_,
    const u16* __restrict__ vt, const float* __restrict__ mask,
    float* __restrict__ out) {
  int id = blockIdx.x;
  int xcd = id & 7, ii = id >> 3;
  int bh = xcd * 6 + (ii >> 4);   // 48 heads, 6 per XCD -> K/V L2-resident
  int qb = ii & 15;
  int l = threadIdx.x & 63, w = threadIdx.x >> 6;
  int lr = l & 15, lg = l >> 4;
  int bidx = bh / NH_, h = bh % NH_;
  int q0 = qb * 128 + w * 32;

  __shared__ __align__(16) float ct_all[4][16 * 68];
  float* ct = ct_all[w];

  const u16* qbase = q + ((size_t)bh * S_ + q0) * HD_;
  const u16* kbase = k_ + (size_t)bh * S_ * HD_;
  const u16* vtb = vt + (size_t)bh * HD_ * S_;
  const float* mrow = mask + (size_t)bidx * S_;

  bf16x8 aq[2][2];
#pragma unroll
  for (int qt = 0; qt < 2; qt++)
#pragma unroll
    for (int h2 = 0; h2 < 2; h2++)
      aq[qt][h2] = *(const bf16x8*)(qbase + (size_t)(16 * qt + lr) * HD_ + 8 * lg + 32 * h2);

  f32x4 ctx[2][4] = {};
  float mrun[2] = {-INFINITY, -INFINITY};
  float lpart[2] = {0.f, 0.f};   // per-lane-group partial softmax denominator

  for (int kb = 0; kb < S_; kb += 64) {
    // K fragments (A-operand rows = kv)
    bf16x8 kf[4][2];
#pragma unroll
    for (int nt = 0; nt < 4; nt++) {
      const u16* kr = kbase + (size_t)(kb + 16 * nt + lr) * HD_ + 8 * lg;
      kf[nt][0] = *(const bf16x8*)(kr);
      kf[nt][1] = *(const bf16x8*)(kr + 32);
    }

    // QK^T swapped: sc[qt][nt][r] = P^T[kb+16nt+4lg+r][q0+16qt+lr]
    f32x4 sc[2][4] = {};
#pragma unroll
    for (int nt = 0; nt < 4; nt++)
#pragma unroll
      for (int qt = 0; qt < 2; qt++) {
        sc[qt][nt] = __builtin_amdgcn_mfma_f32_16x16x32_bf16(kf[nt][0], aq[qt][0], sc[qt][nt], 0, 0, 0);
        sc[qt][nt] = __builtin_amdgcn_mfma_f32_16x16x32_bf16(kf[nt][1], aq[qt][1], sc[qt][nt], 0, 0, 0);
      }

    // V^T A-fragments at permuted columns: vf[nt][h2] = {V^T[d][kb+32h2+4lg..+3],
    //                                                    V^T[d][kb+32h2+16+4lg..+3]}
    union { bf16x8 v; bf16x4 h[2]; } vf[4][2];
#pragma unroll
    for (int nt = 0; nt < 4; nt++) {
      const u16* vr = vtb + (size_t)(16 * nt + lr) * S_ + kb + 4 * lg;
      vf[nt][0].h[0] = *(const bf16x4*)(vr);
      vf[nt][0].h[1] = *(const bf16x4*)(vr + 16);
      vf[nt][1].h[0] = *(const bf16x4*)(vr + 32);
      vf[nt][1].h[1] = *(const bf16x4*)(vr + 48);
    }

    f32x4 mk[4];
#pragma unroll
    for (int nt = 0; nt < 4; nt++)
      mk[nt] = *(const f32x4*)(mrow + kb + 16 * nt + 4 * lg);

    union { bf16x8 v; uu32 u[4]; } pb[2][2];

#pragma unroll
    for (int qt = 0; qt < 2; qt++) {
#pragma unroll
      for (int nt = 0; nt < 4; nt++)
#pragma unroll
        for (int r = 0; r < 4; r++)
          sc[qt][nt][r] = sc[qt][nt][r] + mk[nt][r];   // log2 domain

      float m0_ = fmaxf(fmaxf(sc[qt][0][0], sc[qt][0][1]), fmaxf(sc[qt][0][2], sc[qt][0][3]));
      float m1_ = fmaxf(fmaxf(sc[qt][1][0], sc[qt][1][1]), fmaxf(sc[qt][1][2], sc[qt][1][3]));
      float m2_ = fmaxf(fmaxf(sc[qt][2][0], sc[qt][2][1]), fmaxf(sc[qt][2][2], sc[qt][2][3]));
      float m3_ = fmaxf(fmaxf(sc[qt][3][0], sc[qt][3][1]), fmaxf(sc[qt][3][2], sc[qt][3][3]));
      float vmax = fmaxf(fmaxf(m0_, m1_), fmaxf(m2_, m3_));
      vmax = fmaxf(vmax, __shfl_xor(vmax, 16));
      vmax = fmaxf(vmax, __shfl_xor(vmax, 32));

      // defer-max (T13): only rescale when the running max grew by > THR
      if (!__all(vmax - mrun[qt] <= DEFER_THR)) {
        float mnew = fmaxf(mrun[qt], vmax);
        float scl = exp2_fast(mrun[qt] - mnew);
        mrun[qt] = mnew;
        lpart[qt] *= scl;
#pragma unroll
        for (int nt = 0; nt < 4; nt++)
          ctx[qt][nt] *= scl;
      }

      float psum = 0.f;
#pragma unroll
      for (int nt = 0; nt < 4; nt++)
#pragma unroll
        for (int r = 0; r < 4; r++) {
          sc[qt][nt][r] = exp2_fast(sc[qt][nt][r] - mrun[qt]);
          psum += sc[qt][nt][r];
        }
      lpart[qt] += psum;   // cross-group reduce deferred to epilogue

      // B-fragment = own registers under pi (no shuffles)
#pragma unroll
      for (int h2 = 0; h2 < 2; h2++) {
        pb[qt][h2].u[0] = cvt_pk_bf16(sc[qt][2 * h2][0], sc[qt][2 * h2][1]);
        pb[qt][h2].u[1] = cvt_pk_bf16(sc[qt][2 * h2][2], sc[qt][2 * h2][3]);
        pb[qt][h2].u[2] = cvt_pk_bf16(sc[qt][2 * h2 + 1][0], sc[qt][2 * h2 + 1][1]);
        pb[qt][h2].u[3] = cvt_pk_bf16(sc[qt][2 * h2 + 1][2], sc[qt][2 * h2 + 1][3]);
      }
    }

    // PV: ctx^T[d][q] += V^T[d][pi(kv)] * P^T[pi(kv)][q]
#pragma unroll
    for (int nt = 0; nt < 4; nt++)
#pragma unroll
      for (int qt = 0; qt < 2; qt++) {
        ctx[qt][nt] = __builtin_amdgcn_mfma_f32_16x16x32_bf16(vf[nt][0].v, pb[qt][0].v, ctx[qt][nt], 0, 0, 0);
        ctx[qt][nt] = __builtin_amdgcn_mfma_f32_16x16x32_bf16(vf[nt][1].v, pb[qt][1].v, ctx[qt][nt], 0, 0, 0);
      }
  }

  // epilogue: reduce lpart across groups, then ctx^T -> LDS -> coalesced stores
#pragma unroll
  for (int qt = 0; qt < 2; qt++) {
    float lrun = lpart[qt];
    lrun += __shfl_xor(lrun, 16);
    lrun += __shfl_xor(lrun, 32);
    float inv = 1.f / lrun;
#pragma unroll
    for (int nt = 0; nt < 4; nt++) {
      f32x4 vv = ctx[qt][nt] * inv;
      *(f32x4*)(ct + lr * 68 + 16 * nt + 4 * lg) = vv;   // ct[q=lr][d]
    }
    float* ob = out + ((size_t)bidx * S_ + q0 + 16 * qt) * HID_ + h * HD_;
#pragma unroll
    for (int i = 0; i < 16; i++)
      ob[(size_t)i * HID_ + l] = ct[i * 68 + l];
  }
}

extern "C" void kernel_launch(void* const* d_in, const int* in_sizes, int n_in,
                              void* d_out, int out_size, void* d_ws, size_t ws_size,
                              hipStream_t stream) {
  const float* x    = (const float*)d_in[0];
  const float* mask = (const float*)d_in[1];
  const float* Wq   = (const float*)d_in[2];
  const float* bq   = (const float*)d_in[3];
  const float* Wk   = (const float*)d_in[4];
  const float* bk   = (const float*)d_in[5];
  const float* Wv   = (const float*)d_in[6];
  const float* bv   = (const float*)d_in[7];
  float* out = (float*)d_out;

  char* ws = (char*)d_ws;
  const size_t SZ_X  = (size_t)B_ * S_ * HID_ * 2;
  const size_t SZ_W  = (size_t)3 * HID_ * HID_ * 2;
  u16* xb = (u16*)ws;
  u16* wt = (u16*)(ws + SZ_X);
  u16* q  = (u16*)(ws + SZ_X + SZ_W);
  u16* k  = (u16*)(ws + SZ_X + SZ_W + SZ_X);
  u16* vt = (u16*)(ws + SZ_X + SZ_W + 2 * SZ_X);
  float* mskl = (float*)(ws + SZ_X + SZ_W + 3 * SZ_X);

  int n = B_ * S_ * HID_;
  hipLaunchKernelGGL(cast_x, dim3(n / 1024), dim3(256), 0, stream, x, xb, n);
  hipLaunchKernelGGL(mask_scale, dim3(B_ * S_ / 256), dim3(256), 0, stream,
                     mask, mskl, B_ * S_);
  hipLaunchKernelGGL(wtrans, dim3(24, 24, 3), dim3(256), 0, stream, Wq, Wk, Wv, wt);
  hipLaunchKernelGGL(qkv_gemm, dim3(64, 12, 3), dim3(256), 0, stream,
                     xb, wt, bq, bk, bv, q, k, vt);
  hipLaunchKernelGGL(attn4, dim3(768), dim3(256), 0, stream, q, k, vt, mskl, out);
}